// Round 8
// baseline (132.799 us; speedup 1.0000x reference)
//
#include <hip/hip_runtime.h>
#include <stdint.h>

#define T_SEQ 2048
#define CDIM 1024
#define NHEAD 16
#define HDIM 64
#define MROWS 4096   // B*T

typedef unsigned short u16;
typedef __attribute__((ext_vector_type(8))) short bf16x8;
typedef __attribute__((ext_vector_type(4))) float f32x4;
typedef __attribute__((ext_vector_type(16))) float f32x16;
typedef __attribute__((ext_vector_type(4))) unsigned short u16x4;
typedef __attribute__((ext_vector_type(4))) unsigned int uint4v;

#if __has_builtin(__builtin_amdgcn_exp2f)
#define EXP2(x) __builtin_amdgcn_exp2f(x)
#else
#define EXP2(x) exp2f(x)
#endif

__device__ __forceinline__ u16 f2bf(float f) {
  unsigned u = __builtin_bit_cast(unsigned, f);
  u += 0x7fffu + ((u >> 16) & 1u);
  return (u16)(u >> 16);
}

__device__ __forceinline__ float bf2f(unsigned hw) {
  return __builtin_bit_cast(float, hw << 16);
}

__device__ __forceinline__ unsigned cvt_pk_bf16(float lo, float hi) {
  unsigned r;
  asm("v_cvt_pk_bf16_f32 %0, %1, %2" : "=v"(r) : "v"(lo), "v"(hi));
  return r;
}

// v_permlane32_swap_b32: a' = {a[0:31], b[0:31]}, b' = {a[32:63], b[32:63]}
__device__ __forceinline__ void pls(unsigned &a, unsigned &b) {
  asm("v_permlane32_swap_b32 %0, %1" : "+v"(a), "+v"(b));
}

__device__ __forceinline__ void gll16(const void* g, void* l) {
  __builtin_amdgcn_global_load_lds((__attribute__((address_space(1))) void*)(g),
                                   (__attribute__((address_space(3))) void*)(l),
                                   16, 0, 0);
}

// Raw workgroup barrier WITHOUT the vmcnt(0) drain __syncthreads() implies.
__device__ __forceinline__ void wg_barrier() {
  asm volatile("" ::: "memory");
  __builtin_amdgcn_s_barrier();
  asm volatile("" ::: "memory");
}

// Wait until <= N vector-memory ops outstanding.
#define WAIT_VM(N) do { __builtin_amdgcn_s_waitcnt(0xF00 | 0x70 | (N)); \
                        asm volatile("" ::: "memory"); } while (0)

// One fused conversion pass for all 7 fp32->bf16 inputs.
__global__ __launch_bounds__(256)
void cvt_all(const float* __restrict__ q, const float* __restrict__ k, const float* __restrict__ v,
             const float* __restrict__ wq, const float* __restrict__ wk,
             const float* __restrict__ wv, const float* __restrict__ wo,
             u16* __restrict__ qb, u16* __restrict__ kb, u16* __restrict__ vb,
             u16* __restrict__ wqb, u16* __restrict__ wkb, u16* __restrict__ wvb, u16* __restrict__ wob) {
  int b = blockIdx.x;
  const float* src; u16* dst; int base;
  if (b < 1536) {
    int s = b >> 9;
    src = (s == 0) ? q : (s == 1) ? k : v;
    dst = (s == 0) ? qb : (s == 1) ? kb : vb;
    base = (b & 511) * 2048;
  } else {
    int s = (b - 1536) >> 7;
    src = (s == 0) ? wq : (s == 1) ? wk : (s == 2) ? wv : wo;
    dst = (s == 0) ? wqb : (s == 1) ? wkb : (s == 2) ? wvb : wob;
    base = ((b - 1536) & 127) * 2048;
  }
#pragma unroll
  for (int j = 0; j < 8; ++j) {
    int i = base + j * 256 + threadIdx.x;
    float4 a = ((const float4*)src)[i];
    u16x4 o = { f2bf(a.x), f2bf(a.y), f2bf(a.z), f2bf(a.w) };
    ((u16x4*)dst)[i] = o;
  }
}

// ---------------- GEMM core pieces (unchanged) ----------------

__device__ __forceinline__ void gemm_stage(const u16* Ag, const u16* Bg, u16* Ad, u16* Bd) {
#pragma unroll
  for (int c = 0; c < 4; ++c) {          // 8 vm-ops total
    gll16(Ag + c * 32 * CDIM, Ad + c * 2048);
    gll16(Bg + c * 32 * CDIM, Bd + c * 2048);
  }
}

__device__ __forceinline__ void gemm_compute(const u16* As, const u16* Bs,
                                             f32x4 (&acc)[4][4],
                                             int wr, int wc, int lg, int lr) {
#pragma unroll
  for (int kk = 0; kk < 2; ++kk) {
    bf16x8 af[4], bfr[4];
#pragma unroll
    for (int f = 0; f < 4; ++f) {
      int ra = wr * 64 + f * 16 + lr;
      af[f]  = *(const bf16x8*)((const char*)As + ra * 128 + ((lg * 16 + kk * 64) ^ ((ra & 7) << 4)));
      int rb = wc * 64 + f * 16 + lr;
      bfr[f] = *(const bf16x8*)((const char*)Bs + rb * 128 + ((lg * 16 + kk * 64) ^ ((rb & 7) << 4)));
    }
#pragma unroll
    for (int i = 0; i < 4; ++i)
#pragma unroll
      for (int j = 0; j < 4; ++j)
        acc[i][j] = __builtin_amdgcn_mfma_f32_16x16x32_bf16(af[i], bfr[j], acc[i][j], 0, 0, 0);
  }
}

#define GEMM_KLOOP(As, Bs, Ad0, Bd0, Ad1, Bd1)                                 \
  gemm_stage(Ag, Bg, Ad0, Bd0);                                                \
  _Pragma("unroll 1")                                                          \
  for (int kt = 0; kt < 16; ++kt) {                                            \
    wg_barrier();                                                              \
    int nt = (kt + 1 < 16) ? kt + 1 : 15;                                      \
    if (kt & 1) gemm_stage(Ag + nt * 64, Bg + nt * 64, Ad0, Bd0);              \
    else        gemm_stage(Ag + nt * 64, Bg + nt * 64, Ad1, Bd1);              \
    WAIT_VM(8);                                                                \
    wg_barrier();                                                              \
    gemm_compute((kt & 1) ? As[1] : As[0], (kt & 1) ? Bs[1] : Bs[0],           \
                 acc, wr, wc, lg, lr);                                         \
  }

// Fused Q/K/V projection GEMMs: z = blockIdx.z selects the projection.
__global__ __launch_bounds__(256)
void gemm_qkv(const u16* __restrict__ A0, const u16* __restrict__ A1, const u16* __restrict__ A2,
              const u16* __restrict__ W0, const u16* __restrict__ W1, const u16* __restrict__ W2,
              const float* __restrict__ b0, const float* __restrict__ b1, const float* __restrict__ b2,
              u16* __restrict__ o0, u16* __restrict__ o1, u16* __restrict__ o2,
              float qscale) {
  __shared__ u16 As[2][128 * 64];
  __shared__ u16 Bs[2][128 * 64];
  const int z = blockIdx.z;
  const u16* A   = (z == 0) ? A0 : (z == 1) ? A1 : A2;
  const u16* Bw  = (z == 0) ? W0 : (z == 1) ? W1 : W2;
  const float* bias = (z == 0) ? b0 : (z == 1) ? b1 : b2;
  u16* outp = (z == 0) ? o0 : (z == 1) ? o1 : o2;
  const float scale = (z == 0) ? qscale : 1.0f;

  const int m0 = blockIdx.y * 128;
  const int n0 = blockIdx.x * 128;
  const int tid = threadIdx.x;
  const int w = tid >> 6, l = tid & 63;
  const int wr = w >> 1, wc = w & 1;
  const int lg = l >> 4, lr = l & 15;

  const int row0 = tid >> 3, slot0 = tid & 7;
  const int so = (slot0 ^ (row0 & 7)) << 3;
  const u16* Ag = A  + ((size_t)(m0 + row0)) * CDIM + so;
  const u16* Bg = Bw + ((size_t)(n0 + row0)) * CDIM + so;
  u16* Ad0 = As[0] + w * 512;  u16* Bd0 = Bs[0] + w * 512;
  u16* Ad1 = As[1] + w * 512;  u16* Bd1 = Bs[1] + w * 512;

  f32x4 acc[4][4] = {};

  GEMM_KLOOP(As, Bs, Ad0, Bd0, Ad1, Bd1)

#pragma unroll
  for (int fj = 0; fj < 4; ++fj) {
    int col = n0 + wc * 64 + fj * 16 + lr;
    float bv = bias[col];
    int h = col >> 6, d = col & 63;
#pragma unroll
    for (int fi = 0; fi < 4; ++fi) {
#pragma unroll
      for (int i = 0; i < 4; ++i) {
        int row = m0 + wr * 64 + fi * 16 + lg * 4 + i;
        float val = (acc[fi][fj][i] + bv) * scale;
        int b = row >> 11, t = row & 2047;
        if (z < 2)
          outp[(((size_t)(b * NHEAD + h)) * T_SEQ + t) * HDIM + d] = f2bf(val);
        else
          outp[(((size_t)(b * NHEAD + h)) * HDIM + d) * T_SEQ + t] = f2bf(val);
      }
    }
  }
}

// O-projection: C = A @ Wo^T + bo, fp32 out row-major.
__global__ __launch_bounds__(256)
void gemm_bt0(const u16* __restrict__ A, const u16* __restrict__ Bw,
              const float* __restrict__ bias, float* __restrict__ outp) {
  __shared__ u16 As[2][128 * 64];
  __shared__ u16 Bs[2][128 * 64];
  const int m0 = blockIdx.y * 128;
  const int n0 = blockIdx.x * 128;
  const int tid = threadIdx.x;
  const int w = tid >> 6, l = tid & 63;
  const int wr = w >> 1, wc = w & 1;
  const int lg = l >> 4, lr = l & 15;

  const int row0 = tid >> 3, slot0 = tid & 7;
  const int so = (slot0 ^ (row0 & 7)) << 3;
  const u16* Ag = A  + ((size_t)(m0 + row0)) * CDIM + so;
  const u16* Bg = Bw + ((size_t)(n0 + row0)) * CDIM + so;
  u16* Ad0 = As[0] + w * 512;  u16* Bd0 = Bs[0] + w * 512;
  u16* Ad1 = As[1] + w * 512;  u16* Bd1 = Bs[1] + w * 512;

  f32x4 acc[4][4] = {};

  GEMM_KLOOP(As, Bs, Ad0, Bd0, Ad1, Bd1)

#pragma unroll
  for (int fj = 0; fj < 4; ++fj) {
    int col = n0 + wc * 64 + fj * 16 + lr;
    float bv = bias[col];
#pragma unroll
    for (int fi = 0; fi < 4; ++fi) {
#pragma unroll
      for (int i = 0; i < 4; ++i) {
        int row = m0 + wr * 64 + fi * 16 + lg * 4 + i;
        outp[(size_t)row * CDIM + col] = acc[fi][fj][i] + bv;
      }
    }
  }
}

// ---------------- Flash attention: grid KV-split, partial outputs ----------
// Qh/Kh: [B*H][T][Dh] bf16 (Q pre-scaled by log2e/8). Vt: [B*H][Dh][T] bf16.
// Block = 4 waves x 32 q = 128 q, blockIdx.z = kv half (16 tiles each).
// Each block emits l-normalized partial O (bf16) + (m,l) per q-row; the
// attn_combine kernel merges the two halves (round-7-proven flash merge).
// attn_tile math byte-identical to rounds 6/7.

__device__ __forceinline__ void attn_tile(const char* Kb, const char* Vb,
                                          const bf16x8 (&qf)[4],
                                          f32x16 (&acc)[2], f32x4& lsum, float& m_run,
                                          int lo5, int hi, int swz) {
  // S^T = K @ Q^T : two 32x32 kv-subtiles, K-accumulate over d (4 steps of 16)
  f32x16 s[2] = {};
  const int colK = 16 * hi;
  __builtin_amdgcn_s_setprio(1);
#pragma unroll
  for (int st = 0; st < 4; ++st) {
    bf16x8 k0 = *(const bf16x8*)(Kb + lo5 * 128        + ((32 * st + colK) ^ swz));
    bf16x8 k1 = *(const bf16x8*)(Kb + (lo5 + 32) * 128 + ((32 * st + colK) ^ swz));
    s[0] = __builtin_amdgcn_mfma_f32_32x32x16_bf16(k0, qf[st], s[0], 0, 0, 0);
    s[1] = __builtin_amdgcn_mfma_f32_32x32x16_bf16(k1, qf[st], s[1], 0, 0, 0);
  }
  __builtin_amdgcn_s_setprio(0);

  // lane-local tile max over the 32 scores of this lane's q-row
  float t[8];
#pragma unroll
  for (int i = 0; i < 8; ++i)
    t[i] = fmaxf(fmaxf(s[0][2 * i], s[0][2 * i + 1]), fmaxf(s[1][2 * i], s[1][2 * i + 1]));
  float u0 = fmaxf(fmaxf(t[0], t[1]), fmaxf(t[2], t[3]));
  float u1 = fmaxf(fmaxf(t[4], t[5]), fmaxf(t[6], t[7]));
  float tl = fmaxf(u0, u1);
  if (!__all(tl <= m_run + 8.f)) {       // defer-max (rare path)
    float tmax = fmaxf(tl, __shfl_xor(tl, 32));
    float m_new = fmaxf(m_run, tmax);
    float alpha = EXP2(m_run - m_new);
    lsum[0] *= alpha; lsum[1] *= alpha; lsum[2] *= alpha; lsum[3] *= alpha;
#pragma unroll
    for (int i = 0; i < 16; ++i) { acc[0][i] *= alpha; acc[1][i] *= alpha; }
    m_run = m_new;
  }

  // p = 2^(s - m_run); pack pairs (consecutive kv') to bf16 words
  unsigned pg[2][8];
#pragma unroll
  for (int g = 0; g < 8; ++g) {
    float a0 = EXP2(s[0][2 * g] - m_run), b0 = EXP2(s[0][2 * g + 1] - m_run);
    float a1 = EXP2(s[1][2 * g] - m_run), b1 = EXP2(s[1][2 * g + 1] - m_run);
    lsum[g & 3] += (a0 + b0) + (a1 + b1);
    pg[0][g] = cvt_pk_bf16(a0, b0);
    pg[1][g] = cvt_pk_bf16(a1, b1);
  }

  // Re-shuffle lane<->lane+32 halves into PV B-operand layout.
  bf16x8 pb[4];
#pragma unroll
  for (int sub = 0; sub < 2; ++sub)
#pragma unroll
    for (int ks = 0; ks < 2; ++ks) {
      unsigned w0 = pg[sub][4 * ks + 0], w1 = pg[sub][4 * ks + 1];
      unsigned w2 = pg[sub][4 * ks + 2], w3 = pg[sub][4 * ks + 3];
      pls(w0, w2); pls(w1, w3);
      uint4v tt = { w0, w1, w2, w3 };
      pb[2 * sub + ks] = __builtin_bit_cast(bf16x8, tt);
    }

  // O^T[d][q] += V^T[d][kv] * P^T[kv][q]
  __builtin_amdgcn_s_setprio(1);
#pragma unroll
  for (int ks = 0; ks < 4; ++ks) {
    bf16x8 v0 = *(const bf16x8*)(Vb + lo5 * 128        + ((32 * ks + colK) ^ swz));
    bf16x8 v1 = *(const bf16x8*)(Vb + (lo5 + 32) * 128 + ((32 * ks + colK) ^ swz));
    acc[0] = __builtin_amdgcn_mfma_f32_32x32x16_bf16(v0, pb[ks], acc[0], 0, 0, 0);
    acc[1] = __builtin_amdgcn_mfma_f32_32x32x16_bf16(v1, pb[ks], acc[1], 0, 0, 0);
  }
  __builtin_amdgcn_s_setprio(0);
}

__global__ __launch_bounds__(256, 4)
void attn_fused(const u16* __restrict__ Qh, const u16* __restrict__ Kh,
                const u16* __restrict__ Vt, u16* __restrict__ Op,
                float2* __restrict__ ml) {
  __shared__ u16 Ks[2][64 * 64];
  __shared__ u16 Vs[2][64 * 64];
  const int bh = blockIdx.y;
  const int q0 = blockIdx.x * 128;
  const int half = blockIdx.z;
  const int tid = threadIdx.x;
  const int w = tid >> 6, l = tid & 63;
  const int lo5 = l & 31, hi = l >> 5;
  const int swz = (l & 7) << 4;

  // Q fragments: q-row = q0 + w*32 + lo5, d = 16*st + 8*hi + j
  const u16* qptr = Qh + ((size_t)bh * T_SEQ + q0 + w * 32 + lo5) * HDIM + hi * 8;
  bf16x8 qf[4];
#pragma unroll
  for (int s = 0; s < 4; ++s) qf[s] = *(const bf16x8*)(qptr + 16 * s);

  // staging roles: w=0/1 -> K rows [0-31]/[32-63]; w=2/3 -> V rows.
  const int srow = (w & 1) * 32 + (l >> 3);
  const int soff = ((l & 7) ^ ((l >> 3) & 7)) << 3;
  const u16* Kgs = Kh + ((size_t)bh * T_SEQ + srow) * HDIM + soff;
  const u16* Vgs = Vt + ((size_t)bh * HDIM + srow) * T_SEQ + soff;
  const int isV = w >> 1;

  auto stage = [&](int t, int db) {
    if (!isV) {
      u16* dst = Ks[db] + (w & 1) * 32 * 64;
      const u16* src = Kgs + (size_t)t * 64 * HDIM;
#pragma unroll
      for (int j = 0; j < 4; ++j)
        gll16(src + j * 8 * HDIM, dst + j * 8 * 64);
    } else {
      u16* dst = Vs[db] + (w & 1) * 32 * 64;
      const u16* src = Vgs + t * 64;
#pragma unroll
      for (int j = 0; j < 4; ++j)
        gll16(src + (size_t)j * 8 * T_SEQ, dst + j * 8 * 64);
    }
  };

  f32x16 acc[2] = {};
  f32x4 lsum = {};
  float m_run = -1e30f;
  const int tb = half * 16;

  stage(tb, 0);
#pragma unroll 1
  for (int s = 0; s < 16; ++s) {
    wg_barrier();                               // barA: dbuf^1 free
    int ns = (s + 1 < 16) ? s + 1 : 15;
    stage(tb + ns, (s + 1) & 1);
    WAIT_VM(4);                                 // my step-s loads landed
    wg_barrier();                               // barB: everyone's landed
    attn_tile((const char*)Ks[s & 1], (const char*)Vs[s & 1],
              qf, acc, lsum, m_run, lo5, hi, swz);
  }

  float ls = (lsum[0] + lsum[1]) + (lsum[2] + lsum[3]);
  ls += __shfl_xor(ls, 32);                     // both kv halves of the pair
  float inv = 1.f / ls;

  // l-normalized partial O through per-wave LDS scratch (reuse Ks).
  wg_barrier();                                 // staging buffers free
  char* os = (char*)&Ks[0][0] + w * 4096;       // 4KB/wave: [32 q][64 d] bf16
#pragma unroll
  for (int dsub = 0; dsub < 2; ++dsub)
#pragma unroll
    for (int gg = 0; gg < 4; ++gg) {
      unsigned wa = cvt_pk_bf16(acc[dsub][4 * gg + 0] * inv, acc[dsub][4 * gg + 1] * inv);
      unsigned wb = cvt_pk_bf16(acc[dsub][4 * gg + 2] * inv, acc[dsub][4 * gg + 3] * inv);
      uint2 wv = { wa, wb };
      int byte = lo5 * 128 + (((32 * dsub + 8 * gg + 4 * hi) * 2) ^ swz);
      *(uint2*)(os + byte) = wv;
    }
  u16* orow = Op + ((size_t)(half * 32 + bh) * T_SEQ + q0 + w * 32) * HDIM;
#pragma unroll
  for (int c = 0; c < 4; ++c) {
    int qq = 8 * c + (l >> 3);
    uint4v ov = *(const uint4v*)(os + qq * 128 + ((16 * (l & 7)) ^ ((qq & 7) << 4)));
    *(uint4v*)(orow + qq * HDIM + (l & 7) * 8) = ov;
  }
  if (hi == 0)
    ml[(size_t)(half * 32 + bh) * T_SEQ + q0 + w * 32 + lo5] = make_float2(m_run, ls);
}

// Merge the two kv-half partials: O = a0*O0n + a1*O1n, a_i = 2^(m_i-M)*l_i/Z.
__global__ __launch_bounds__(256)
void attn_combine(const u16* __restrict__ Op, const float2* __restrict__ ml,
                  u16* __restrict__ Ao) {
  int task0 = blockIdx.x * 256 + threadIdx.x;
#pragma unroll 1
  for (int it = 0; it < 4; ++it) {
    int task = task0 + it * 131072;        // 524288 tasks: (bh, q, chunk8)
    int chunk = task & 7;
    int q  = (task >> 3) & 2047;
    int bh = task >> 14;
    float2 ml0 = ml[(size_t)bh * T_SEQ + q];
    float2 ml1 = ml[(size_t)(32 + bh) * T_SEQ + q];
    float M = fmaxf(ml0.x, ml1.x);
    float w0 = EXP2(ml0.x - M) * ml0.y;
    float w1 = EXP2(ml1.x - M) * ml1.y;
    float zi = 1.f / (w0 + w1);
    float a0 = w0 * zi, a1 = w1 * zi;
    const u16* p0 = Op + ((size_t)bh * T_SEQ + q) * HDIM + chunk * 8;
    const u16* p1 = Op + ((size_t)(32 + bh) * T_SEQ + q) * HDIM + chunk * 8;
    uint4v o0 = *(const uint4v*)p0;
    uint4v o1 = *(const uint4v*)p1;
    uint4v ov;
#pragma unroll
    for (int j = 0; j < 4; ++j) {
      float lo = a0 * bf2f(o0[j] & 0xffffu)  + a1 * bf2f(o1[j] & 0xffffu);
      float hi = a0 * bf2f(o0[j] >> 16)      + a1 * bf2f(o1[j] >> 16);
      ov[j] = cvt_pk_bf16(lo, hi);
    }
    int b = bh >> 4, h = bh & 15;
    *(uint4v*)(Ao + ((size_t)(b * T_SEQ + q)) * CDIM + h * HDIM + chunk * 8) = ov;
  }
}

extern "C" void kernel_launch(void* const* d_in, const int* in_sizes, int n_in,
                              void* d_out, int out_size, void* d_ws, size_t ws_size,
                              hipStream_t stream) {
  const float* q  = (const float*)d_in[0];
  const float* k  = (const float*)d_in[1];
  const float* v  = (const float*)d_in[2];
  const float* Wq = (const float*)d_in[3];
  const float* bq = (const float*)d_in[4];
  const float* Wk = (const float*)d_in[5];
  const float* bk = (const float*)d_in[6];
  const float* Wv = (const float*)d_in[7];
  const float* bv = (const float*)d_in[8];
  const float* Wo = (const float*)d_in[9];
  const float* bo = (const float*)d_in[10];

  char* ws = (char*)d_ws;
  size_t off = 0;
  auto alloc = [&](size_t n) { void* p = ws + off; off += (n + 255) & ~(size_t)255; return p; };
  const size_t NX = (size_t)MROWS * CDIM;  // 4M elements
  const size_t NW = (size_t)CDIM * CDIM;   // 1M elements
  u16* qb  = (u16*)alloc(NX * 2);
  u16* kb  = (u16*)alloc(NX * 2);
  u16* vb  = (u16*)alloc(NX * 2);
  u16* Wqb = (u16*)alloc(NW * 2);
  u16* Wkb = (u16*)alloc(NW * 2);
  u16* Wvb = (u16*)alloc(NW * 2);
  u16* Wob = (u16*)alloc(NW * 2);
  u16* Qhp = (u16*)alloc(NX * 2);
  u16* Khp = (u16*)alloc(NX * 2);
  u16* Vtp = (u16*)alloc(NX * 2);
  u16* Aop = (u16*)alloc(NX * 2);

  // After gemm_qkv, qb/kb/vb are dead: alias attn partials onto them.
  // Op: 2 halves x 4M bf16 = 16MB spans qb+kb (contiguous); ml (1MB) in vb.
  u16* Op = qb;
  float2* mlp = (float2*)vb;

  cvt_all<<<2048, 256, 0, stream>>>(q, k, v, Wq, Wk, Wv, Wo,
                                    qb, kb, vb, Wqb, Wkb, Wvb, Wob);

  const float qscale = 0.18033688011112042f; // log2(e)/8 -> softmax in exp2 domain
  gemm_qkv<<<dim3(CDIM / 128, MROWS / 128, 3), 256, 0, stream>>>(
      qb, kb, vb, Wqb, Wkb, Wvb, bq, bk, bv, Qhp, Khp, Vtp, qscale);

  attn_fused<<<dim3(T_SEQ / 128, 32, 2), 256, 0, stream>>>(Qhp, Khp, Vtp, Op, mlp);
  attn_combine<<<512, 256, 0, stream>>>(Op, mlp, Aop);

  gemm_bt0<<<dim3(CDIM / 128, MROWS / 128), 256, 0, stream>>>(Aop, Wob, bo, (float*)d_out);

  (void)in_sizes; (void)n_in; (void)out_size; (void)ws_size;
}